// Round 2
// baseline (132.730 us; speedup 1.0000x reference)
//
#include <hip/hip_runtime.h>

// FeatureShader: pytorch3d softmax_rgb_blend + TexturesVertex barycentric gather.
// N,H,W,K,C = 4,256,256,8,16.
//
// R4 = R3 with the compile fix (nontemporal store needs a clang vector type,
// not HIP's float2 class). Theory unchanged:
// - gather predicate w > 1e-17 (strict superset of w > denom*1e-7, since
//   denom >= delta >= 1e-10): available BEFORE the denom butterfly, so the
//   vfeat gather issues ~150+ cy earlier and the denom reduction runs in the
//   shadow of the in-flight loads. Numerically closer to the reference.
// - faces[] fetched unconditionally right after p2f (all pix_to_face >= 0 in
//   this dataset; clamped for safety): its L2 latency hides under the whole
//   softmax phase, removing one serial memory hop from the gather region.
// - nontemporal loads for stream-once arrays (z/d/p2f/bary) + nontemporal
//   output store: keeps L2/L3 for the reused vfeat/faces tables.

constexpr int KK = 8;
constexpr int CC = 16;

typedef float floatx2 __attribute__((ext_vector_type(2)));

__global__ __launch_bounds__(256) void feature_shader(
    const float* __restrict__ dists,
    const float* __restrict__ zbuf,
    const float* __restrict__ bary,
    const float* __restrict__ vfeat,
    const float* __restrict__ bg,
    const int*   __restrict__ p2f,
    const int*   __restrict__ faces,
    float* __restrict__ out,
    int n)   // n = N*H*W*K
{
    const float INV_SIGMA = 1e4f;          // 1/SIGMA
    const float INV_GAMMA = 1e4f;          // 1/GAMMA
    const float EPS       = 1e-10f;
    const float ZFAR      = 100.f;
    const float INV_SPAN  = 1.f / 99.f;    // 1/(ZFAR-ZNEAR)

    int t = blockIdx.x * blockDim.x + threadIdx.x;
    if (t >= n) return;
    int k = t & (KK - 1);

    // Perfectly coalesced per-slot loads; stream-once -> nontemporal.
    float z  = __builtin_nontemporal_load(zbuf  + t);
    float dd = __builtin_nontemporal_load(dists + t);
    int   f  = __builtin_nontemporal_load(p2f   + t);

    // Unconditional faces fetch: issued now so its L2/L3 latency overlaps the
    // entire softmax phase below. f >= 0 always holds for this data; clamp so
    // a negative index can never fault.
    int fc = (f >= 0) ? f : 0;
    int v0 = faces[fc * 3 + 0];
    int v1 = faces[fc * 3 + 1];
    int v2 = faces[fc * 3 + 2];

    float zinv = (f >= 0) ? (ZFAR - z) * INV_SPAN : 0.f;

    // Group max over the 8-lane k-group.
    float m = zinv;
    m = fmaxf(m, __shfl_xor(m, 1));
    m = fmaxf(m, __shfl_xor(m, 2));
    m = fmaxf(m, __shfl_xor(m, 4));
    m = fmaxf(m, EPS);

    float delta = fmaxf(__expf((EPS - m) * INV_GAMMA), EPS);
    float prob  = (f >= 0) ? 1.f / (1.f + __expf(dd * INV_SIGMA)) : 0.f;
    float w     = prob * __expf((zinv - m) * INV_GAMMA);

    // Superset of the exact test w > denom*1e-7: denom >= delta >= 1e-10, so
    // any lane failing w > 1e-17 would also have been skipped by the exact
    // test. Lanes in between now contribute (like the reference does).
    bool keep = (w > 1e-17f);

    // Phase 1 of the gather: issue all loads. vfeat addresses depend only on
    // the already-arrived faces data, so the 12 float4 loads go out
    // immediately; the denom butterfly below executes in their shadow.
    float  b0, b1, b2;
    float4 a0[4], a1[4], a2[4];
    if (keep) {
        const float* bp = bary + (size_t)t * 3;
        b0 = __builtin_nontemporal_load(bp + 0) * w;
        b1 = __builtin_nontemporal_load(bp + 1) * w;
        b2 = __builtin_nontemporal_load(bp + 2) * w;
        const float4* t0 = (const float4*)(vfeat + (size_t)v0 * CC);
        const float4* t1 = (const float4*)(vfeat + (size_t)v1 * CC);
        const float4* t2 = (const float4*)(vfeat + (size_t)v2 * CC);
        #pragma unroll
        for (int j = 0; j < 4; ++j) {
            a0[j] = t0[j];
            a1[j] = t1[j];
            a2[j] = t2[j];
        }
    }

    // Group sum -> denominator (overlaps the in-flight vfeat loads).
    float denom = w;
    denom += __shfl_xor(denom, 1);
    denom += __shfl_xor(denom, 2);
    denom += __shfl_xor(denom, 4);
    denom += delta;

    float acc[CC];
    #pragma unroll
    for (int c = 0; c < CC; ++c) acc[c] = 0.f;

    // Phase 2 of the gather: consume the loaded data.
    if (keep) {
        #pragma unroll
        for (int j = 0; j < 4; ++j) {
            acc[j * 4 + 0] = b0 * a0[j].x + b1 * a1[j].x + b2 * a2[j].x;
            acc[j * 4 + 1] = b0 * a0[j].y + b1 * a1[j].y + b2 * a2[j].y;
            acc[j * 4 + 2] = b0 * a0[j].z + b1 * a1[j].z + b2 * a2[j].z;
            acc[j * 4 + 3] = b0 * a0[j].w + b1 * a1[j].w + b2 * a2[j].w;
        }
    }

    // Reduce-scatter across the 8-lane group: 16 -> 8 -> 4 -> 2 channels.
    // Stage distance d: lane keeps low half of its block if (k & d) == 0.
    {   // d=4: 16 -> 8
        bool low = (k & 4) == 0;
        float nxt[8];
        #pragma unroll
        for (int i = 0; i < 8; ++i) {
            float send = low ? acc[8 + i] : acc[i];
            float recv = __shfl_xor(send, 4);
            nxt[i] = (low ? acc[i] : acc[8 + i]) + recv;
        }
        #pragma unroll
        for (int i = 0; i < 8; ++i) acc[i] = nxt[i];
    }
    {   // d=2: 8 -> 4
        bool low = (k & 2) == 0;
        float nxt[4];
        #pragma unroll
        for (int i = 0; i < 4; ++i) {
            float send = low ? acc[4 + i] : acc[i];
            float recv = __shfl_xor(send, 2);
            nxt[i] = (low ? acc[i] : acc[4 + i]) + recv;
        }
        #pragma unroll
        for (int i = 0; i < 4; ++i) acc[i] = nxt[i];
    }
    {   // d=1: 4 -> 2; lane k ends with channels [2k, 2k+1]
        bool low = (k & 1) == 0;
        float nxt[2];
        #pragma unroll
        for (int i = 0; i < 2; ++i) {
            float send = low ? acc[2 + i] : acc[i];
            float recv = __shfl_xor(send, 1);
            nxt[i] = (low ? acc[i] : acc[2 + i]) + recv;
        }
        acc[0] = nxt[0];
        acc[1] = nxt[1];
    }

    float2 g = ((const float2*)bg)[k];
    float inv_den = 1.f / denom;
    floatx2 o;
    o.x = (acc[0] + delta * g.x) * inv_den;
    o.y = (acc[1] + delta * g.y) * inv_den;
    __builtin_nontemporal_store(o, (floatx2*)out + t);   // coalesced dwordx2
}

extern "C" void kernel_launch(void* const* d_in, const int* in_sizes, int n_in,
                              void* d_out, int out_size, void* d_ws, size_t ws_size,
                              hipStream_t stream) {
    const float* dists = (const float*)d_in[0];
    const float* zbuf  = (const float*)d_in[1];
    const float* bary  = (const float*)d_in[2];
    const float* vfeat = (const float*)d_in[3];
    const float* bg    = (const float*)d_in[4];
    const int*   p2f   = (const int*)d_in[5];
    const int*   faces = (const int*)d_in[6];
    float* out = (float*)d_out;

    int n = in_sizes[0];                   // N*H*W*K = 2097152
    int block = 256;
    int grid = (n + block - 1) / block;    // 8192 blocks

    hipLaunchKernelGGL(feature_shader, dim3(grid), dim3(block), 0, stream,
                       dists, zbuf, bary, vfeat, bg, p2f, faces, out, n);
}